// Round 8
// baseline (37292.499 us; speedup 1.0000x reference)
//
#include <hip/hip_runtime.h>
#include <math.h>

#define T_SEQ 4096
typedef unsigned long long ull;

__device__ __forceinline__ float sigmoidf_(float x) {
  return 1.0f / (1.0f + expf(-x));
}

__device__ __forceinline__ ull pack_h(int tag, float h) {
  return ((ull)(unsigned)tag << 32) | (ull)__float_as_uint(h);
}

// System-scope (MALL) load/store — the only always-fresh exchange ops
// validated this session (R0-R7: cached probes stale forever; atomics
// serialize per-lane).
__device__ __forceinline__ ull ld_mall(const ull* p) {
  ull v;
  asm volatile("global_load_dwordx2 %0, %1, off sc0 sc1\n\ts_waitcnt vmcnt(0)"
               : "=v"(v) : "v"(p) : "memory");
  return v;
}
__device__ __forceinline__ void st_mall(ull* p, ull v) {
  asm volatile("global_store_dwordx2 %0, %1, off sc0 sc1"
               :: "v"(p), "v"(v) : "memory");
}
__device__ __forceinline__ ull poll_u64(const ull* p, unsigned want) {
  for (;;) {
    ull v = ld_mall(p);
    if ((unsigned)(v >> 32) == want) return v;
  }
}
__device__ __forceinline__ float poll_mall(const ull* p, unsigned want) {
  return __uint_as_float((unsigned)poll_u64(p, want));
}
// Issue-early / wait-late prefetch (guide T14 pattern): issue now, drain with
// vmcnt(0)+sched_barrier(0) at use.
__device__ __forceinline__ void ld_issue(const ull* p, ull& v) {
  asm volatile("global_load_dwordx2 %0, %1, off sc0 sc1"
               : "=v"(v) : "v"(p) : "memory");
}
__device__ __forceinline__ void vm0() {
  asm volatile("s_waitcnt vmcnt(0)" ::: "memory");
  __builtin_amdgcn_sched_barrier(0);
}
__device__ __forceinline__ void lgkm0() {
  asm volatile("s_waitcnt lgkmcnt(0)" ::: "memory");
}
// lgkm-only barrier (used only for init and the worker WGs).
__device__ __forceinline__ void bar() {
  lgkm0();
  __builtin_amdgcn_s_barrier();
  asm volatile("" ::: "memory");
}

// LDS h layout: pad between k-halves so the two per-instruction addresses hit
// different banks (R7 lesson: 2.3e8 conflicts from 512B-apart halves).
__device__ __forceinline__ int HXI(int k) { return k + ((k >> 7) << 3); }

// ---- named-register weight fragments + anti-rematerialization pin ----------
#define DECL_W8(p) float4 p##0, p##1, p##2, p##3, p##4, p##5, p##6, p##7
#define LOAD_W8(p, src) do { const float4* _s = (const float4*)(src); \
  p##0=_s[0]; p##1=_s[1]; p##2=_s[2]; p##3=_s[3]; \
  p##4=_s[4]; p##5=_s[5]; p##6=_s[6]; p##7=_s[7]; } while (0)
#define PIN4(v4) asm volatile("" : "+v"((v4).x), "+v"((v4).y), \
                                   "+v"((v4).z), "+v"((v4).w))
#define PIN_W8(p) do { PIN4(p##0); PIN4(p##1); PIN4(p##2); PIN4(p##3); \
  PIN4(p##4); PIN4(p##5); PIN4(p##6); PIN4(p##7); } while (0)
#define FMA4(acc, W_, H_) do { acc = fmaf((W_).x, (H_).x, acc); \
  acc = fmaf((W_).y, (H_).y, acc); acc = fmaf((W_).z, (H_).z, acc); \
  acc = fmaf((W_).w, (H_).w, acc); } while (0)
#define G8(acc, p, off) do { \
  { float4 hv = h4[off + 0]; FMA4(acc, p##0, hv); } \
  { float4 hv = h4[off + 1]; FMA4(acc, p##1, hv); } \
  { float4 hv = h4[off + 2]; FMA4(acc, p##2, hv); } \
  { float4 hv = h4[off + 3]; FMA4(acc, p##3, hv); } \
  { float4 hv = h4[off + 4]; FMA4(acc, p##4, hv); } \
  { float4 hv = h4[off + 5]; FMA4(acc, p##5, hv); } \
  { float4 hv = h4[off + 6]; FMA4(acc, p##6, hv); } \
  { float4 hv = h4[off + 7]; FMA4(acc, p##7, hv); } \
} while (0)

// X[t][k] = emb[tokens[t]][k], as float4
__global__ void gather_emb(const int* __restrict__ tokens,
                           const float4* __restrict__ emb4,
                           float4* __restrict__ X4) {
  int i = blockIdx.x * 256 + threadIdx.x;   // i < 4096*128
  int t = i >> 7;
  int q = i & 127;
  X4[i] = emb4[(long)tokens[t] * 128 + q];
}

// P[t][j] = bias_ih[j] + bias_hh[j] + sum_k X[src(t)][k] * W[j][k]
__global__ __launch_bounds__(256) void gemm_proj(
    const float* __restrict__ Xf, const float* __restrict__ Xb, int revb,
    const float* __restrict__ Wf, const float* __restrict__ Wb,
    const float* __restrict__ bihf, const float* __restrict__ bhhf,
    const float* __restrict__ bihb, const float* __restrict__ bhhb,
    float* __restrict__ Pf, float* __restrict__ Pb, int K)
{
  const int dirb = blockIdx.z;
  const float* X  = dirb ? Xb : Xf;
  const float* W  = dirb ? Wb : Wf;
  const float* bih = dirb ? bihb : bihf;
  const float* bhh = dirb ? bhhb : bhhf;
  float* Pp = dirb ? Pb : Pf;
  const int rev = dirb ? revb : 0;

  const int bn = blockIdx.x;
  const int bm = blockIdx.y;
  const int tid = threadIdx.x;
  const int tx = tid & 15, ty = tid >> 4;

  __shared__ float Xs[16][68];
  __shared__ float Ws[16][68];

  float acc[4][4] = {{0.f}};

  const int lrow = tid >> 2;
  const int lk4  = (tid & 3) * 4;
  const int xrow = bm * 64 + lrow;
  const int xsrc = rev ? (4095 - xrow) : xrow;
  const float* xptr = X + (long)xsrc * K + lk4;
  const float* wptr = W + (long)(bn * 64 + lrow) * K + lk4;

  for (int k0 = 0; k0 < K; k0 += 16) {
    float4 xv = *(const float4*)(xptr + k0);
    float4 wv = *(const float4*)(wptr + k0);
    __syncthreads();
    Xs[lk4 + 0][lrow] = xv.x; Xs[lk4 + 1][lrow] = xv.y;
    Xs[lk4 + 2][lrow] = xv.z; Xs[lk4 + 3][lrow] = xv.w;
    Ws[lk4 + 0][lrow] = wv.x; Ws[lk4 + 1][lrow] = wv.y;
    Ws[lk4 + 2][lrow] = wv.z; Ws[lk4 + 3][lrow] = wv.w;
    __syncthreads();
    #pragma unroll
    for (int kk = 0; kk < 16; ++kk) {
      float4 a = *(const float4*)(&Xs[kk][ty * 4]);
      float4 b = *(const float4*)(&Ws[kk][tx * 4]);
      acc[0][0] = fmaf(a.x, b.x, acc[0][0]); acc[0][1] = fmaf(a.x, b.y, acc[0][1]);
      acc[0][2] = fmaf(a.x, b.z, acc[0][2]); acc[0][3] = fmaf(a.x, b.w, acc[0][3]);
      acc[1][0] = fmaf(a.y, b.x, acc[1][0]); acc[1][1] = fmaf(a.y, b.y, acc[1][1]);
      acc[1][2] = fmaf(a.y, b.z, acc[1][2]); acc[1][3] = fmaf(a.y, b.w, acc[1][3]);
      acc[2][0] = fmaf(a.z, b.x, acc[2][0]); acc[2][1] = fmaf(a.z, b.y, acc[2][1]);
      acc[2][2] = fmaf(a.z, b.z, acc[2][2]); acc[2][3] = fmaf(a.z, b.w, acc[2][3]);
      acc[3][0] = fmaf(a.w, b.x, acc[3][0]); acc[3][1] = fmaf(a.w, b.y, acc[3][1]);
      acc[3][2] = fmaf(a.w, b.z, acc[3][2]); acc[3][3] = fmaf(a.w, b.w, acc[3][3]);
    }
  }

  const int c0 = bn * 64 + tx * 4;
  #pragma unroll
  for (int i = 0; i < 4; ++i) {
    const int r = bm * 64 + ty * 4 + i;
    float4 o4;
    o4.x = acc[i][0] + bih[c0 + 0] + bhh[c0 + 0];
    o4.y = acc[i][1] + bih[c0 + 1] + bhh[c0 + 1];
    o4.z = acc[i][2] + bih[c0 + 2] + bhh[c0 + 2];
    o4.w = acc[i][3] + bih[c0 + 3] + bhh[c0 + 3];
    *(float4*)(&Pp[(long)r * 1024 + c0]) = o4;
  }
}

// Fused recurrence, free-running design. Grid 48 x 512:
//   bx 0-15  : L0 WGs   (d=bx&1, w=bx>>1, 32 cells, K=256, P0 precomputed)
//   bx 16-31 : L1 WGs   (d=bx&1, w1=(bx-16)>>1, 32 cells, K=256 via Whh1;
//                        Wih1*h0 term arrives as tagged Pih1 ring entries)
//   bx 32-47 : workers  (d=bx&1, wid=(bx-32)>>1; stream Pih1[s]=Wih1*h0(s)+b
//                        for s == wid mod 8, lagging L0 freely)
// L0/L1 WG: waves 0-3 compute (8 lanes/cell: gate=(t>>1)&3, kh=t&1; R7's
// verified in-wave gate combine), waves 4-7 dedicated pollers (56 lanes each)
// that never barrier. Handshake = monotonic LDS tags:
//   rdy[p][wv]  : pollers filled hx2[p] sibling cells for step s (tag s+1)
//   cdone[p][wv]: compute wrote own cells of hx2[p] at C(s-1)   (tag s)
//   bdone[p][wv]: compute finished reading hx2[p] at B(s)       (tag s+1)
__global__ __launch_bounds__(512, 1) void lstm_fused(
    const float* __restrict__ P0f, const float* __restrict__ P0b,
    const float* __restrict__ Whh0f, const float* __restrict__ Whh0b,
    const float* __restrict__ Wih1f, const float* __restrict__ Whh1f,
    const float* __restrict__ bih1f, const float* __restrict__ bhh1f,
    const float* __restrict__ Wih1b, const float* __restrict__ Whh1b,
    const float* __restrict__ bih1b, const float* __restrict__ bhh1b,
    float* __restrict__ out,
    ull* __restrict__ ring0,    // h0 truth ring [2][4096][256]
    ull* __restrict__ h1x,      // h1 slots      [2][2 par][256]
    ull* __restrict__ ppring,   // Pih1 ring     [2][64][1024]
    ull* __restrict__ prog)     // L1 progress   [2]
{
  const int bx = blockIdx.x;
  const int t  = threadIdx.x;
  const int d  = bx & 1;

  __shared__ __align__(16) float hx2[2][264];   // padded via HXI
  __shared__ int flags[2][12];                  // [0..3]rdy [4..7]cdone [8..11]bdone
  __shared__ __align__(16) float hs[256];       // worker: staged h0(s)
  __shared__ __align__(16) float bsumS[1024];   // worker: bias sums

  ull* ring = ring0 + (long)d * T_SEQ * 256;

  if (bx < 32) {
    // =================== recurrent WG (L0 or L1) ===========================
    const bool isL1 = (bx >= 16);
    const int w = (isL1 ? (bx - 16) : bx) >> 1;
    const int wbase = w * 32;
    const int wv = t >> 6;

    // init
    if (t < 256) hx2[0][HXI(t)] = 0.0f;
    if (t < 24) ((int*)flags)[t] = 0;
    bar();

    if (t < 256) {
      // ---------------- compute lanes ------------------------------------
      const int cell = t >> 3, gate = (t >> 1) & 3, kh = t & 1;
      const int j = gate * 256 + wbase + cell;
      const float* W = isL1 ? (d ? Whh1b : Whh1f) : (d ? Whh0b : Whh0f);
      const float* P = d ? P0b : P0f;
      ull* slot = h1x + (long)d * 512;
      ull* ppr  = ppring + (long)d * 64 * 1024;
      float* hout = d ? (out + 2048 + (long)4095 * 512 + 256) : (out + 2048);
      const long hstr = d ? -512 : 512;
      const int ppidx = w * 128 + cell * 4 + gate;  // Pih1 ring layout
      volatile int* flv = (volatile int*)flags;

      DECL_W8(wa); DECL_W8(wb); DECL_W8(wc); DECL_W8(wd);
      {
        const float* ws_ = W + (long)j * 256 + kh * 128;
        LOAD_W8(wa, ws_); LOAD_W8(wb, ws_ + 32);
        LOAD_W8(wc, ws_ + 64); LOAD_W8(wd, ws_ + 96);
        PIN_W8(wa); PIN_W8(wb); PIN_W8(wc); PIN_W8(wd);
      }

      float pv_cur = 0.0f;     // L0: P value for step s
      ull ppn = 0;             // L1: in-flight Pih1 prefetch
      if (!isL1) pv_cur = P[j];
      else ld_issue(ppr + 0 * 1024 + ppidx, ppn);

      float c_prev = 0.0f;

      for (int s = 0; s < T_SEQ; ++s) {
        const int p = s & 1;
        if (s > 0) {   // wait sibling fills (tag s+1) + own-cell writes (tag s)
          for (;;) {
            volatile int* f = flv + p * 12;
            if (f[0] >= s + 1 && f[1] >= s + 1 && f[2] >= s + 1 && f[3] >= s + 1 &&
                f[4] >= s && f[5] >= s && f[6] >= s && f[7] >= s) break;
          }
        }
        float base_g;
        if (!isL1) {
          base_g = pv_cur;
        } else {
          vm0();
          ull ppc = ppn;
          if ((unsigned)(ppc >> 32) != (unsigned)(s + 1))
            ppc = poll_u64(ppr + (long)(s & 63) * 1024 + ppidx, (unsigned)(s + 1));
          base_g = __uint_as_float((unsigned)ppc);
          if (s + 1 < T_SEQ)
            ld_issue(ppr + (long)((s + 1) & 63) * 1024 + ppidx, ppn);
        }

        // B: matvec over K=256 (kh-half in registers)
        const float4* h4 = (const float4*)(&hx2[p][kh * 136]);
        float a0 = 0.f, a1 = 0.f, a2 = 0.f, a3 = 0.f;
        G8(a0, wa, 0); G8(a1, wb, 8); G8(a2, wc, 16); G8(a3, wd, 24);
        float sum = (a0 + a1) + (a2 + a3);
        float tot = sum + __shfl_xor(sum, 1);     // join k-halves
        lgkm0();
        if ((t & 63) == 0) flv[p * 12 + 8 + wv] = s + 1;   // bdone

        float pv_next = 0.0f;
        if (!isL1 && s + 1 < T_SEQ) pv_next = P[(long)(s + 1) * 1024 + j];

        // C: act + in-wave quad combine (verified R7 algebra)
        float g = base_g + tot;
        float act = ((t & 6) == 4) ? tanhf(g) : sigmoidf_(g);
        float y  = __shfl_xor(act, 2);
        float zx = __shfl_xor(act, 4);
        float zy = __shfl_xor(y, 4);
        const bool l1b = (t & 2), h1b = (t & 4);
        float i_ = h1b ? (l1b ? zy : zx) : (l1b ? y : act);
        float f_ = h1b ? (l1b ? zx : zy) : (l1b ? act : y);
        float g_ = h1b ? (l1b ? y : act) : (l1b ? zy : zx);
        float o_ = h1b ? (l1b ? act : y) : (l1b ? zx : zy);
        float c = f_ * c_prev + i_ * g_;
        c_prev = c;
        float h = o_ * tanhf(c);

        const int gc = wbase + cell;
        if ((t & 7) == 0) hx2[(s + 1) & 1][HXI(gc)] = h;   // own-cell bypass
        lgkm0();
        if ((t & 63) == 0) flv[((s + 1) & 1) * 12 + 4 + wv] = s + 1;  // cdone

        if ((t & 7) == 0) {
          ull pk = pack_h(s + 1, h);
          if (!isL1) {
            st_mall(ring + (long)s * 256 + gc, pk);
            if (s == T_SEQ - 1) {
              out[d * 256 + gc] = c;
              out[1024 + d * 256 + gc] = h;
            }
          } else {
            st_mall(&slot[(s & 1) * 256 + gc], pk);
            hout[(long)s * hstr + gc] = h;
            if (w == 0 && t == 0) st_mall(prog + d, pack_h(s + 1, 0.f));
            if (s == T_SEQ - 1) {
              out[512 + d * 256 + gc] = c;
              out[1024 + 512 + d * 256 + gc] = h;
            }
          }
        }
        pv_cur = pv_next;
      }
    } else {
      // ---------------- poller waves (free-running, no barriers) ---------
      const int wv4 = wv - 4, lane = t & 63;
      const bool on = lane < 56;
      const int widx = wv4 * 56 + lane;                    // 0..223
      const int pcell = (widx < wbase) ? widx : widx + 32; // skip own 32
      ull* slot = h1x + (long)d * 512;
      volatile int* flv = (volatile int*)flags;

      for (int s = 1; s < T_SEQ; ++s) {
        const int p = s & 1;
        float v = 0.0f;
        if (on) {
          v = isL1
            ? poll_mall(slot + (long)((s - 1) & 1) * 256 + pcell, (unsigned)s)
            : poll_mall(ring + (long)(s - 1) * 256 + pcell, (unsigned)s);
        }
        // wait B(s-2) on this parity before overwriting hx2[p]
        for (;;) {
          volatile int* f = flv + p * 12 + 8;
          if (f[0] >= s - 1 && f[1] >= s - 1 && f[2] >= s - 1 && f[3] >= s - 1)
            break;
        }
        if (on) hx2[p][HXI(pcell)] = v;
        lgkm0();
        if (lane == 0) flv[p * 12 + wv4] = s + 1;          // rdy
      }
    }
  } else {
    // =================== Pih1 streaming workers ============================
    const int wid = (bx - 32) >> 1;
    const float* Wih = d ? Wih1b : Wih1f;
    const float* bih = d ? bih1b : bih1f;
    const float* bhh = d ? bhh1b : bhh1f;
    ull* ppr = ppring + (long)d * 64 * 1024;
    ull* progp = prog + d;
    const int wv = t >> 6, lane = t & 63;

    for (int i = t; i < 1024; i += 512) bsumS[i] = bih[i] + bhh[i];
    bar();

    for (long s = wid; s < T_SEQ; s += 8) {
      if (t < 256) hs[t] = poll_mall(ring + s * 256 + t, (unsigned)(s + 1));
      if (s >= 56 && t == 0) {   // ring-overwrite guard (depth 64, margin 48)
        for (;;) {
          ull v = ld_mall(progp);
          if ((int)(unsigned)(v >> 32) >= (int)(s - 47)) break;
        }
      }
      bar();
      const long slotbase = (s & 63) * 1024;
      #pragma unroll 4
      for (int r = 0; r < 128; ++r) {
        const int j = wv * 128 + r;
        float4 w4 = *(const float4*)&Wih[(long)j * 256 + lane * 4];
        float4 hv = *(const float4*)&hs[lane * 4];
        float pa = w4.x * hv.x + w4.y * hv.y + w4.z * hv.z + w4.w * hv.w;
        pa += __shfl_xor(pa, 1);  pa += __shfl_xor(pa, 2);
        pa += __shfl_xor(pa, 4);  pa += __shfl_xor(pa, 8);
        pa += __shfl_xor(pa, 16); pa += __shfl_xor(pa, 32);
        if (lane == 0) {
          const int g = j >> 8, rem = j & 255, w1 = rem >> 5, cl = rem & 31;
          const int idx = w1 * 128 + cl * 4 + g;
          st_mall(&ppr[slotbase + idx], pack_h((int)s + 1, pa + bsumS[j]));
        }
      }
      bar();   // protect hs before next-stage rewrite
    }
  }
}

extern "C" void kernel_launch(void* const* d_in, const int* in_sizes, int n_in,
                              void* d_out, int out_size, void* d_ws, size_t ws_size,
                              hipStream_t stream) {
  const int*   tokens = (const int*)d_in[0];
  const float* emb    = (const float*)d_in[1];
  const float* fWih0 = (const float*)d_in[2];
  const float* fWhh0 = (const float*)d_in[3];
  const float* fbih0 = (const float*)d_in[4];
  const float* fbhh0 = (const float*)d_in[5];
  const float* fWih1 = (const float*)d_in[6];
  const float* fWhh1 = (const float*)d_in[7];
  const float* fbih1 = (const float*)d_in[8];
  const float* fbhh1 = (const float*)d_in[9];
  const float* bWih0 = (const float*)d_in[10];
  const float* bWhh0 = (const float*)d_in[11];
  const float* bbih0 = (const float*)d_in[12];
  const float* bbhh0 = (const float*)d_in[13];
  const float* bWih1 = (const float*)d_in[14];
  const float* bWhh1 = (const float*)d_in[15];
  const float* bbih1 = (const float*)d_in[16];
  const float* bbhh1 = (const float*)d_in[17];

  float* out = (float*)d_out;
  float* ws  = (float*)d_ws;

  // Workspace layout (float offsets):
  //   [0, 4194304)          h0 rings [2][4096][256] u64 (16 MB); X overlaps
  //                         the first 8 MB (dead after gemm_proj, memset after)
  //   [4194304,  8388608)   P0f (4096x1024)
  //   [8388608, 12582912)   P0b (4096x1024)
  //   [12582912, 12584960)  h1x [2][2][256] u64 (8 KB)
  //   [12584960, 12847104)  ppring [2][64][1024] u64 (1 MB)
  //   [12847104, 12847108)  prog [2] u64
  float* X   = ws;
  float* P0f = ws + 4194304;
  float* P0b = ws + 8388608;
  ull* ring0  = (ull*)ws;
  ull* h1x    = (ull*)(ws + 12582912);
  ull* ppring = (ull*)(ws + 12584960);
  ull* prog   = (ull*)(ws + 12847104);

  gather_emb<<<2048, 256, 0, stream>>>(tokens, (const float4*)emb, (float4*)X);

  gemm_proj<<<dim3(16, 64, 2), 256, 0, stream>>>(
      X, X, 1, fWih0, bWih0, fbih0, fbhh0, bbih0, bbhh0, P0f, P0b, 512);

  hipMemsetAsync(ring0, 0, (size_t)2 * T_SEQ * 256 * sizeof(ull), stream);
  hipMemsetAsync(h1x, 0, 1024 * sizeof(ull), stream);
  hipMemsetAsync(ppring, 0, (size_t)2 * 64 * 1024 * sizeof(ull), stream);
  hipMemsetAsync(prog, 0, 2 * sizeof(ull), stream);

  lstm_fused<<<dim3(48), 512, 0, stream>>>(
      P0f, P0b, fWhh0, bWhh0,
      fWih1, fWhh1, fbih1, fbhh1,
      bWih1, bWhh1, bbih1, bbhh1,
      out, ring0, h1x, ppring, prog);
}

// Round 10
// 8829.311 us; speedup vs baseline: 4.2237x; 4.2237x over previous
//
#include <hip/hip_runtime.h>
#include <math.h>

#define T_SEQ 4096
typedef unsigned long long ull;

__device__ __forceinline__ float sigmoidf_(float x) {
  return 1.0f / (1.0f + expf(-x));
}

__device__ __forceinline__ ull pack_h(int tag, float h) {
  return ((ull)(unsigned)tag << 32) | (ull)__float_as_uint(h);
}

// System-scope (MALL) exchange — the only always-fresh primitives validated
// this session (R0-R8). The vmcnt(0) INSIDE the asm is load-bearing: no load
// ever escapes the statement, so no async register clobber (R9's NaN was a
// deep-poll variant that returned with probes still in flight).
__device__ __forceinline__ ull ld_mall(const ull* p) {
  ull v;
  asm volatile("global_load_dwordx2 %0, %1, off sc0 sc1\n\ts_waitcnt vmcnt(0)"
               : "=v"(v) : "v"(p) : "memory");
  return v;
}
__device__ __forceinline__ void st_mall(ull* p, ull v) {
  asm volatile("global_store_dwordx2 %0, %1, off sc0 sc1"
               :: "v"(p), "v"(v) : "memory");
}
__device__ __forceinline__ float poll_mall(const ull* p, unsigned want) {
  for (;;) {
    ull v = ld_mall(p);
    if ((unsigned)(v >> 32) == want) return __uint_as_float((unsigned)v);
  }
}

// Raw workgroup barrier: drains LDS (lgkm) only — publishes/prefetches stay
// in flight across it.
__device__ __forceinline__ void bar() {
  asm volatile("s_waitcnt lgkmcnt(0)" ::: "memory");
  __builtin_amdgcn_s_barrier();
  asm volatile("" ::: "memory");
}

// Padded LDS index: +8 floats per 128-float slice -> slice bases on distinct
// banks (R7 unpadded: 2.3e8 conflicts; R8 padded: 65K).
__device__ __forceinline__ int HXI(int k) { return k + ((k >> 7) << 3); }

// ---- named-register weight fragments + anti-rematerialization pin ----------
#define DECL_W8(p) float4 p##0, p##1, p##2, p##3, p##4, p##5, p##6, p##7
#define LOAD_W8(p, src) do { const float4* _s = (const float4*)(src); \
  p##0=_s[0]; p##1=_s[1]; p##2=_s[2]; p##3=_s[3]; \
  p##4=_s[4]; p##5=_s[5]; p##6=_s[6]; p##7=_s[7]; } while (0)
#define PIN4(v4) asm volatile("" : "+v"((v4).x), "+v"((v4).y), \
                                   "+v"((v4).z), "+v"((v4).w))
#define PIN_W8(p) do { PIN4(p##0); PIN4(p##1); PIN4(p##2); PIN4(p##3); \
  PIN4(p##4); PIN4(p##5); PIN4(p##6); PIN4(p##7); } while (0)
#define FMA4(acc, W_, H_) do { acc = fmaf((W_).x, (H_).x, acc); \
  acc = fmaf((W_).y, (H_).y, acc); acc = fmaf((W_).z, (H_).z, acc); \
  acc = fmaf((W_).w, (H_).w, acc); } while (0)
#define G8(acc, p, off) do { \
  { float4 hv = h4[off + 0]; FMA4(acc, p##0, hv); } \
  { float4 hv = h4[off + 1]; FMA4(acc, p##1, hv); } \
  { float4 hv = h4[off + 2]; FMA4(acc, p##2, hv); } \
  { float4 hv = h4[off + 3]; FMA4(acc, p##3, hv); } \
  { float4 hv = h4[off + 4]; FMA4(acc, p##4, hv); } \
  { float4 hv = h4[off + 5]; FMA4(acc, p##5, hv); } \
  { float4 hv = h4[off + 6]; FMA4(acc, p##6, hv); } \
  { float4 hv = h4[off + 7]; FMA4(acc, p##7, hv); } \
} while (0)

// X[t][k] = emb[tokens[t]][k], as float4
__global__ void gather_emb(const int* __restrict__ tokens,
                           const float4* __restrict__ emb4,
                           float4* __restrict__ X4) {
  int i = blockIdx.x * 256 + threadIdx.x;   // i < 4096*128
  int t = i >> 7;
  int q = i & 127;
  X4[i] = emb4[(long)tokens[t] * 128 + q];
}

// P[t][j] = bias_ih[j] + bias_hh[j] + sum_k X[src(t)][k] * W[j][k]
__global__ __launch_bounds__(256) void gemm_proj(
    const float* __restrict__ Xf, const float* __restrict__ Xb, int revb,
    const float* __restrict__ Wf, const float* __restrict__ Wb,
    const float* __restrict__ bihf, const float* __restrict__ bhhf,
    const float* __restrict__ bihb, const float* __restrict__ bhhb,
    float* __restrict__ Pf, float* __restrict__ Pb, int K)
{
  const int dirb = blockIdx.z;
  const float* X  = dirb ? Xb : Xf;
  const float* W  = dirb ? Wb : Wf;
  const float* bih = dirb ? bihb : bihf;
  const float* bhh = dirb ? bhhb : bhhf;
  float* Pp = dirb ? Pb : Pf;
  const int rev = dirb ? revb : 0;

  const int bn = blockIdx.x;
  const int bm = blockIdx.y;
  const int tid = threadIdx.x;
  const int tx = tid & 15, ty = tid >> 4;

  __shared__ float Xs[16][68];
  __shared__ float Ws[16][68];

  float acc[4][4] = {{0.f}};

  const int lrow = tid >> 2;
  const int lk4  = (tid & 3) * 4;
  const int xrow = bm * 64 + lrow;
  const int xsrc = rev ? (4095 - xrow) : xrow;
  const float* xptr = X + (long)xsrc * K + lk4;
  const float* wptr = W + (long)(bn * 64 + lrow) * K + lk4;

  for (int k0 = 0; k0 < K; k0 += 16) {
    float4 xv = *(const float4*)(xptr + k0);
    float4 wv = *(const float4*)(wptr + k0);
    __syncthreads();
    Xs[lk4 + 0][lrow] = xv.x; Xs[lk4 + 1][lrow] = xv.y;
    Xs[lk4 + 2][lrow] = xv.z; Xs[lk4 + 3][lrow] = xv.w;
    Ws[lk4 + 0][lrow] = wv.x; Ws[lk4 + 1][lrow] = wv.y;
    Ws[lk4 + 2][lrow] = wv.z; Ws[lk4 + 3][lrow] = wv.w;
    __syncthreads();
    #pragma unroll
    for (int kk = 0; kk < 16; ++kk) {
      float4 a = *(const float4*)(&Xs[kk][ty * 4]);
      float4 b = *(const float4*)(&Ws[kk][tx * 4]);
      acc[0][0] = fmaf(a.x, b.x, acc[0][0]); acc[0][1] = fmaf(a.x, b.y, acc[0][1]);
      acc[0][2] = fmaf(a.x, b.z, acc[0][2]); acc[0][3] = fmaf(a.x, b.w, acc[0][3]);
      acc[1][0] = fmaf(a.y, b.x, acc[1][0]); acc[1][1] = fmaf(a.y, b.y, acc[1][1]);
      acc[1][2] = fmaf(a.y, b.z, acc[1][2]); acc[1][3] = fmaf(a.y, b.w, acc[1][3]);
      acc[2][0] = fmaf(a.z, b.x, acc[2][0]); acc[2][1] = fmaf(a.z, b.y, acc[2][1]);
      acc[2][2] = fmaf(a.z, b.z, acc[2][2]); acc[2][3] = fmaf(a.z, b.w, acc[2][3]);
      acc[3][0] = fmaf(a.w, b.x, acc[3][0]); acc[3][1] = fmaf(a.w, b.y, acc[3][1]);
      acc[3][2] = fmaf(a.w, b.z, acc[3][2]); acc[3][3] = fmaf(a.w, b.w, acc[3][3]);
    }
  }

  const int c0 = bn * 64 + tx * 4;
  #pragma unroll
  for (int i = 0; i < 4; ++i) {
    const int r = bm * 64 + ty * 4 + i;
    float4 o4;
    o4.x = acc[i][0] + bih[c0 + 0] + bhh[c0 + 0];
    o4.y = acc[i][1] + bih[c0 + 1] + bhh[c0 + 1];
    o4.z = acc[i][2] + bih[c0 + 2] + bhh[c0 + 2];
    o4.w = acc[i][3] + bih[c0 + 3] + bhh[c0 + 3];
    *(float4*)(&Pp[(long)r * 1024 + c0]) = o4;
  }
}

// Fused 2-layer bidirectional LSTM recurrence. 24 WGs (12/dir), SINGLE
// lgkm-only barrier per step, parity-buffered padded hx2, in-wave K-reduce +
// quad gate combine (R7 algebra, HW-passed twice), drained MALL exchange.
//   bx 0-7  : L0 (d=bx&1, w=bx>>1, 64 cells; lane: cell=t>>3 gate=(t>>1)&3
//             kh=t&1; kh=0 lanes poll siblings, kh=1 lanes own P-loads,
//             c-state and publishes)
//   bx 8-23 : L1 (d=bx&1, w1=(bx-8)>>1, 32 cells; lane: cell=t>>4
//             gate=(t>>2)&3 kq=t&3; the 15-of-16 non-publish lanes poll)
__global__ __launch_bounds__(512, 1) void lstm_fused(
    const float* __restrict__ P0f, const float* __restrict__ P0b,
    const float* __restrict__ Whh0f, const float* __restrict__ Whh0b,
    const float* __restrict__ Wih1f, const float* __restrict__ Whh1f,
    const float* __restrict__ bih1f, const float* __restrict__ bhh1f,
    const float* __restrict__ Wih1b, const float* __restrict__ Whh1b,
    const float* __restrict__ bih1b, const float* __restrict__ bhh1b,
    float* __restrict__ out,
    ull* __restrict__ ring0,    // h0 ring [2][4096][256]
    ull* __restrict__ h1x)      // h1 slots [2][2 par][256]
{
  const int bx = blockIdx.x;
  const int t  = threadIdx.x;
  const int d  = bx & 1;

  __shared__ __align__(16) float hx2[2][536];   // parity x padded(512)

  ull* ring = ring0 + (long)d * T_SEQ * 256;

  if (t < 256) { hx2[0][HXI(t)] = 0.0f; hx2[0][HXI(t + 256)] = 0.0f; }
  bar();

  if (bx < 8) {
    // ======================= Layer 0 (4 WGs/dir, 64 cells) ==================
    const int w = bx >> 1;
    const int wbase = w * 64;
    const float* __restrict__ P = d ? P0b : P0f;
    const float* __restrict__ W = d ? Whh0b : Whh0f;

    const int cell = t >> 3, gate = (t >> 1) & 3, kh = t & 1;
    const int j = gate * 256 + wbase + cell;
    const int pe = t >> 1;                            // poller idx (kh==0)
    const int pcell = (pe < wbase) ? pe : pe + 64;    // valid when pe<192

    DECL_W8(wa); DECL_W8(wb); DECL_W8(wc); DECL_W8(wd);
    {
      const float* ws_ = W + (long)j * 256 + kh * 128;
      LOAD_W8(wa, ws_); LOAD_W8(wb, ws_ + 32);
      LOAD_W8(wc, ws_ + 64); LOAD_W8(wd, ws_ + 96);
      PIN_W8(wa); PIN_W8(wb); PIN_W8(wc); PIN_W8(wd);
    }

    float pv_cur = 0.0f, c_prev = 0.0f;
    if (kh) pv_cur = P[j];

    for (int s = 0; s < T_SEQ; ++s) {
      const int p = s & 1;
      // issue next-step P early (kh=1 lanes; consumed at C(s+1))
      float pv_next = 0.0f;
      if (kh && s + 1 < T_SEQ) pv_next = P[(long)(s + 1) * 1024 + j];
      // A: poll sibling h(s-1) (kh=0, pe<192; own cells via LDS bypass)
      if (!kh && pe < 192 && s > 0)
        hx2[p][HXI(pcell)] =
            poll_mall(ring + (long)(s - 1) * 256 + pcell, (unsigned)s);
      bar();   // hx2[p] complete

      // B: matvec (kh-half in registers) + in-wave K-join
      const float4* h4 = (const float4*)&hx2[p][kh * 136];
      float a0 = 0.f, a1 = 0.f, a2 = 0.f, a3 = 0.f;
      G8(a0, wa, 0); G8(a1, wb, 8); G8(a2, wc, 16); G8(a3, wd, 24);
      float sum = (a0 + a1) + (a2 + a3);
      float tot = sum + __shfl_xor(sum, 1);

      // C: act + quad combine + publish (kh=1 plane only)
      if (kh) {
        float g = pv_cur + tot;
        pv_cur = pv_next;
        float act = (gate == 2) ? tanhf(g) : sigmoidf_(g);
        float y  = __shfl_xor(act, 2);
        float zx = __shfl_xor(act, 4);
        float zy = __shfl_xor(y, 4);
        const bool l1b = (t & 2), h1b = (t & 4);
        float i_ = h1b ? (l1b ? zy : zx) : (l1b ? y : act);
        float f_ = h1b ? (l1b ? zx : zy) : (l1b ? act : y);
        float g_ = h1b ? (l1b ? y : act) : (l1b ? zy : zx);
        float o_ = h1b ? (l1b ? act : y) : (l1b ? zx : zy);
        float c = f_ * c_prev + i_ * g_;
        c_prev = c;
        float h = o_ * tanhf(c);
        if (gate == 0) {   // one lane per cell: t&7 == 1
          const int gc = wbase + cell;
          hx2[p ^ 1][HXI(gc)] = h;                    // own-cell LDS bypass
          st_mall(ring + (long)s * 256 + gc, pack_h(s + 1, h));
          if (s == T_SEQ - 1) {
            out[d * 256 + gc] = c;            // cell_memories layer 0
            out[1024 + d * 256 + gc] = h;     // hidden_states layer 0
          }
        }
      }
    }
  } else {
    // ======================= Layer 1 (8 WGs/dir, 32 cells) ==================
    const int w1 = (bx - 8) >> 1;
    const int wbase1 = w1 * 32;
    const float* __restrict__ Wih = d ? Wih1b : Wih1f;
    const float* __restrict__ Whh = d ? Whh1b : Whh1f;
    const float* __restrict__ bihp = d ? bih1b : bih1f;
    const float* __restrict__ bhhp = d ? bhh1b : bhh1f;
    ull* slot = h1x + (long)d * 512;                  // [parity][256]
    float* hout = d ? (out + 2048 + (long)4095 * 512 + 256) : (out + 2048);
    const long hstr = d ? -512 : 512;

    const int cell = t >> 4, gate = (t >> 2) & 3, kq = t & 3;
    const int j = gate * 256 + wbase1 + cell;
    const int r16 = t & 15;
    const int pg = (t >> 4) * 15 + ((r16 < 1) ? r16 : r16 - 1); // r16!=1 only

    DECL_W8(ua); DECL_W8(ub); DECL_W8(uc); DECL_W8(ud);
    {
      const float* us_ = (kq < 2) ? (Wih + (long)j * 256 + kq * 128)
                                  : (Whh + (long)j * 256 + (kq - 2) * 128);
      LOAD_W8(ua, us_); LOAD_W8(ub, us_ + 32);
      LOAD_W8(uc, us_ + 64); LOAD_W8(ud, us_ + 96);
      PIN_W8(ua); PIN_W8(ub); PIN_W8(uc); PIN_W8(ud);
    }
    const float bsum = bihp[j] + bhhp[j];
    float c_prev = 0.0f;

    for (int s = 0; s < T_SEQ; ++s) {
      const int p = s & 1;
      // A: poll h0(s) (256 targets) + sibling h1(s-1) (224 targets)
      if (r16 != 1) {
        if (pg < 256) {
          hx2[p][HXI(pg)] =
              poll_mall(ring + (long)s * 256 + pg, (unsigned)(s + 1));
        } else {
          const int q1 = pg - 256;
          const int pc1 = (q1 < wbase1) ? q1 : q1 + 32;
          hx2[p][HXI(256 + pc1)] =
              poll_mall(slot + (long)((s + 1) & 1) * 256 + pc1, (unsigned)s);
        }
      }
      bar();   // hx2[p][0..511] complete

      // B: matvec over K=512 (kq-quarter in registers) + in-wave K-join
      const float4* h4 = (const float4*)&hx2[p][kq * 136];
      float a0 = 0.f, a1 = 0.f, a2 = 0.f, a3 = 0.f;
      G8(a0, ua, 0); G8(a1, ub, 8); G8(a2, uc, 16); G8(a3, ud, 24);
      float sum = (a0 + a1) + (a2 + a3);
      float r1 = sum + __shfl_xor(sum, 1);
      float r2 = r1 + __shfl_xor(r1, 2);

      // C: act + quad combine + publish (kq=1 plane only)
      if (kq == 1) {
        float g = bsum + r2;
        float act = (gate == 2) ? tanhf(g) : sigmoidf_(g);
        float y  = __shfl_xor(act, 4);
        float zx = __shfl_xor(act, 8);
        float zy = __shfl_xor(y, 8);
        const bool l1b = (t & 4), h1b = (t & 8);
        float i_ = h1b ? (l1b ? zy : zx) : (l1b ? y : act);
        float f_ = h1b ? (l1b ? zx : zy) : (l1b ? act : y);
        float g_ = h1b ? (l1b ? y : act) : (l1b ? zy : zx);
        float o_ = h1b ? (l1b ? act : y) : (l1b ? zx : zy);
        float c = f_ * c_prev + i_ * g_;
        c_prev = c;
        float h = o_ * tanhf(c);
        if (gate == 0) {   // one lane per cell: t&15 == 1
          const int gc = wbase1 + cell;
          hx2[p ^ 1][HXI(256 + gc)] = h;              // own-cell LDS bypass
          st_mall(&slot[(long)p * 256 + gc], pack_h(s + 1, h));
          hout[(long)s * hstr + gc] = h;
          if (s == T_SEQ - 1) {
            out[512 + d * 256 + gc] = c;          // cell_memories layer 1
            out[1536 + d * 256 + gc] = h;         // hidden_states layer 1
          }
        }
      }
    }
  }
}

extern "C" void kernel_launch(void* const* d_in, const int* in_sizes, int n_in,
                              void* d_out, int out_size, void* d_ws, size_t ws_size,
                              hipStream_t stream) {
  const int*   tokens = (const int*)d_in[0];
  const float* emb    = (const float*)d_in[1];
  const float* fWih0 = (const float*)d_in[2];
  const float* fWhh0 = (const float*)d_in[3];
  const float* fbih0 = (const float*)d_in[4];
  const float* fbhh0 = (const float*)d_in[5];
  const float* fWih1 = (const float*)d_in[6];
  const float* fWhh1 = (const float*)d_in[7];
  const float* fbih1 = (const float*)d_in[8];
  const float* fbhh1 = (const float*)d_in[9];
  const float* bWih0 = (const float*)d_in[10];
  const float* bWhh0 = (const float*)d_in[11];
  const float* bbih0 = (const float*)d_in[12];
  const float* bbhh0 = (const float*)d_in[13];
  const float* bWih1 = (const float*)d_in[14];
  const float* bWhh1 = (const float*)d_in[15];
  const float* bbih1 = (const float*)d_in[16];
  const float* bbhh1 = (const float*)d_in[17];

  float* out = (float*)d_out;
  float* ws  = (float*)d_ws;

  // Workspace layout (float offsets):
  //   [0, 4194304)          h0 rings [2][4096][256] u64 (16 MB); X overlaps
  //                         the first 8 MB (dead after gemm_proj, memset after)
  //   [4194304,  8388608)   P0f (4096x1024)
  //   [8388608, 12582912)   P0b (4096x1024)
  //   [12582912, 12584960)  h1x [2][2][256] u64 (8 KB)
  float* X   = ws;
  float* P0f = ws + 4194304;
  float* P0b = ws + 8388608;
  ull* ring0 = (ull*)ws;
  ull* h1x   = (ull*)(ws + 12582912);

  gather_emb<<<2048, 256, 0, stream>>>(tokens, (const float4*)emb, (float4*)X);

  // Layer 0 input projections (K=512); b-direction reads X time-reversed.
  gemm_proj<<<dim3(16, 64, 2), 256, 0, stream>>>(
      X, X, 1, fWih0, bWih0, fbih0, fbhh0, bbih0, bbhh0, P0f, P0b, 512);

  // Reset exchange buffers (tag 0 = "not ready" / "h(-1)=0").
  hipMemsetAsync(ring0, 0, (size_t)2 * T_SEQ * 256 * sizeof(ull), stream);
  hipMemsetAsync(h1x, 0, 1024 * sizeof(ull), stream);

  // Fused recurrence: 24 WGs (12 per direction), placement-independent.
  lstm_fused<<<dim3(24), 512, 0, stream>>>(
      P0f, P0b, fWhh0, bWhh0,
      fWih1, fWhh1, fbih1, fbhh1,
      bWih1, bWhh1, bbih1, bbhh1,
      out, ring0, h1x);
}